// Round 24
// baseline (708.052 us; speedup 1.0000x reference)
//
#include <hip/hip_runtime.h>
#include <math.h>

#define D 256
#define KC 64
#define NPTS 8192
#define TRI ((D*(D+1))/2)

#define WSZ 33920             // 16B-aligned, cumulative 16B/row-staggered packed triangle
#define FR_PER_CL 72          // triangular 16x16x32 fragments per cluster
#define SH_PER_CL (FR_PER_CL*512)           // shorts per cluster per plane
#define SLAB_SH ((size_t)(3*SH_PER_CL))     // shorts per cluster slab (3 planes)

typedef __attribute__((ext_vector_type(8))) short short8;
typedef __attribute__((ext_vector_type(4))) float f32x4;

// row base: 16B-aligned, CUMULATIVE 16B-per-row stagger (injective; bases walk
// the 128B bank period)
__device__ __forceinline__ int wb(int r) {
  return ((r*(r+1)/2 + 3) & ~3) + (r << 2);
}
__device__ __forceinline__ unsigned short f2bf(float f) {                   // RNE float->bf16 bits
  unsigned u = __float_as_uint(f);
  u = (u + 0x7fffu + ((u >> 16) & 1u)) >> 16;
  return (unsigned short)u;
}
__device__ __forceinline__ float bf2f(unsigned short s) { return __uint_as_float(((unsigned)s) << 16); }
__device__ __forceinline__ float rdlane(float v, int l) {
  return __uint_as_float(__builtin_amdgcn_readlane(__float_as_uint(v), l));
}
__device__ __forceinline__ int frag_off(int I) { int a = I >> 1; return (I & 1) ? (a+1)*(a+1) : a*(a+1); }

// ---------------------------------------------------------------------------
// K1: blocked Cholesky (B=32 panels), 512 threads (proven non-spilling:
// VGPR 128): serial register diag core (U on diag), TRSM (2 threads/row),
// SYRK. Writes L-triangle (U on diag blocks) to slab head.  [FROZEN]
// ---------------------------------------------------------------------------
__global__ __launch_bounds__(512, 1) void gmm_chol(
    const float* __restrict__ var, unsigned short* __restrict__ planes)
{
  __shared__ float W[WSZ];
  __shared__ float Tbuf[32*36];

  const int k = blockIdx.x, tid = threadIdx.x;
  const int lane = tid & 63, wid = tid >> 6;
  const float* A = var + (size_t)k*D*D;

  for (int idx = tid; idx < TRI; idx += 512) {
    int i = (int)((sqrtf(8.0f*(float)idx + 1.0f) - 1.0f)*0.5f);
    while ((i+1)*(i+2)/2 <= idx) ++i;
    while (i*(i+1)/2 > idx) --i;
    const int p = idx - i*(i+1)/2;
    W[wb(i) + p] = A[i*D + p];
  }
  __syncthreads();

#pragma unroll 1
  for (int jb = 0; jb < 8; ++jb) {
    const int c0 = jb*32, c1 = c0 + 32, m = 256 - c1;

    if (wid == 0 && lane < 32) {
      const int rbase = wb(c0 + lane) + c0;
      float Arow[32];
#pragma unroll
      for (int p = 0; p < 32; ++p) Arow[p] = W[rbase + p];   // p>lane: garbage, never escapes

      float mydinv = 0.0f;
#pragma unroll
      for (int j = 0; j < 32; ++j) {
        const float dj = sqrtf(rdlane(Arow[j], j));
        const float dinv = 1.0f / dj;
        const float c = Arow[j] * dinv;
        Arow[j] = (lane == j) ? dj : c;
        mydinv = (lane == j) ? dinv : mydinv;
#pragma unroll
        for (int p = j + 1; p < 32; ++p) {
          const float cp = rdlane(c, p);
          Arow[p] -= c * cp;
        }
      }

      // G11 = inv(L11), forward substitution fused in place
#pragma unroll
      for (int p = 0; p < 32; ++p) {
        const float lp = (lane > p) ? Arow[p] : 0.0f;
#pragma unroll
        for (int j = 0; j < p; ++j) {
          const float fin = (0.0f - Arow[j]) * mydinv;
          Arow[j] = (lane == p) ? fin : Arow[j];
        }
        Arow[p] = (lane == p) ? mydinv : Arow[p];
#pragma unroll
        for (int j = 0; j < p; ++j) {
          const float gpj = rdlane(Arow[j], p);
          Arow[j] += lp * gpj;
        }
        const float gpp = rdlane(Arow[p], p);
        Arow[p] = (lane > p) ? (lp * gpp) : Arow[p];
      }

#pragma unroll
      for (int j = 0; j < 32; ++j) {
        if (j <= lane) W[rbase + j] = Arow[j];
        Tbuf[lane*36 + j] = (j <= lane) ? Arow[j] : 0.0f;
      }
    }
    __syncthreads();

    // TRSM: 2 threads/row; preload rows (b128), barrier, compute+write
    {
      const int m2 = 2*m;
      const int r = tid >> 1, jh = tid & 1;
      const int rb = wb(c1 + r) + c0;
      float row[32];
      if (tid < m2) {
#pragma unroll
        for (int p4 = 0; p4 < 8; ++p4) {
          const float4 v = *reinterpret_cast<const float4*>(&W[rb + p4*4]);
          row[p4*4+0] = v.x; row[p4*4+1] = v.y; row[p4*4+2] = v.z; row[p4*4+3] = v.w;
        }
      }
      __syncthreads();
      if (tid < m2) {
        const int j0 = jh*16;
#pragma unroll 1
        for (int j = j0; j < j0 + 16; ++j) {
          const float* up = &Tbuf[j*36];
          float s0 = 0.f, s1 = 0.f, s2 = 0.f, s3 = 0.f;
#pragma unroll
          for (int p4 = 0; p4 < 8; ++p4) {
            const float4 u = *reinterpret_cast<const float4*>(&up[p4*4]);
            s0 += row[p4*4+0]*u.x; s1 += row[p4*4+1]*u.y;
            s2 += row[p4*4+2]*u.z; s3 += row[p4*4+3]*u.w;
          }
          W[rb + j] = (s0 + s1) + (s2 + s3);
        }
      }
    }
    __syncthreads();

    // SYRK: trailing triangle -= L21*L21^T, b128 reads along p
    if (m > 0) {
      const int nt = m >> 2, ntri = nt*(nt+1)/2;
      for (int tau = tid; tau < ntri; tau += 512) {
        int ti = (int)((sqrtf(8.0f*(float)tau + 1.0f) - 1.0f)*0.5f);
        while ((ti+1)*(ti+2)/2 <= tau) ++ti;
        while (ti*(ti+1)/2 > tau) --ti;
        const int tl = tau - ti*(ti+1)/2;
        const int i0 = c1 + ti*4, l0 = c1 + tl*4;
        const int ib[4] = {wb(i0)+c0, wb(i0+1)+c0, wb(i0+2)+c0, wb(i0+3)+c0};
        const int lb[4] = {wb(l0)+c0, wb(l0+1)+c0, wb(l0+2)+c0, wb(l0+3)+c0};
        float acc[4][4];
#pragma unroll
        for (int a = 0; a < 4; ++a)
#pragma unroll
          for (int b = 0; b < 4; ++b) acc[a][b] = 0.0f;
#pragma unroll
        for (int p4 = 0; p4 < 8; ++p4) {
          float4 av[4], bv[4];
#pragma unroll
          for (int a = 0; a < 4; ++a) av[a] = *reinterpret_cast<const float4*>(&W[ib[a] + p4*4]);
#pragma unroll
          for (int b = 0; b < 4; ++b) bv[b] = *reinterpret_cast<const float4*>(&W[lb[b] + p4*4]);
#pragma unroll
          for (int a = 0; a < 4; ++a)
#pragma unroll
            for (int b = 0; b < 4; ++b)
              acc[a][b] += av[a].x*bv[b].x + av[a].y*bv[b].y + av[a].z*bv[b].z + av[a].w*bv[b].w;
        }
#pragma unroll
        for (int a = 0; a < 4; ++a)
#pragma unroll
          for (int b = 0; b < 4; ++b) {
            const int rr = i0 + a, cc = l0 + b;
            if (cc <= rr) W[wb(rr) + cc] -= acc[a][b];
          }
      }
    }
    __syncthreads();
  }

  float* Wgk = (float*)(planes + (size_t)k*SLAB_SH);
  for (int idx = tid; idx < WSZ; idx += 512) Wgk[idx] = W[idx];
}

// ---------------------------------------------------------------------------
// K2: column-parallel triangular inversion, 7 blocks/cluster (one J each;
// J=7 has no off-diag work). Each block loads only rows >= 32J (all its
// recurrence touches), runs the in-place column recurrence for J, writes
// back rows >= 32(J+1) of column-block J (disjoint across blocks).
// ---------------------------------------------------------------------------
__global__ __launch_bounds__(512, 1) void gmm_inv3(unsigned short* __restrict__ planes)
{
  __shared__ float W[WSZ];
  __shared__ float Tbuf[32*36];

  const int b = blockIdx.x, k = b/7, J = b - 7*(b/7);
  const int tid = threadIdx.x;
  float* Wgk = (float*)(planes + (size_t)k*SLAB_SH);
  const int base = wb(32*J);           // 16B-aligned; rows >= 32J live at [base, WSZ)
  for (int idx = base + tid; idx < WSZ; idx += 512) W[idx] = Wgk[idx];
  __syncthreads();

  const int i0 = tid >> 4;
  const int j0g = (tid & 15) * 2;

#pragma unroll 1
  for (int I = J + 1; I < 8; ++I) {
    float acc0 = 0.f, acc1 = 0.f;
    for (int K = J; K < I; ++K) {
      const int abase = wb(32*I + i0) + 32*K;
      const int brow = 32*K, bcol = 32*J + j0g;
      const bool dK = (K == J);
#pragma unroll
      for (int p4 = 0; p4 < 8; ++p4) {
        const float4 av = *reinterpret_cast<const float4*>(&W[abase + p4*4]);
        const float a4[4] = {av.x, av.y, av.z, av.w};
#pragma unroll
        for (int pp = 0; pp < 4; ++pp) {
          const int p = p4*4 + pp;
          const float2 bv = *reinterpret_cast<const float2*>(&W[wb(brow + p) + bcol]);
          float b0 = bv.x, b1 = bv.y;
          if (dK) { if (j0g > p) b0 = 0.f; if (j0g + 1 > p) b1 = 0.f; }
          acc0 += a4[pp]*b0; acc1 += a4[pp]*b1;
        }
      }
    }
    Tbuf[i0*36 + j0g] = acc0;
    Tbuf[i0*36 + j0g + 1] = acc1;
    __syncthreads();

    float g0 = 0.f, g1 = 0.f;
    const int ubase = wb(32*I + i0) + 32*I;
#pragma unroll
    for (int p4 = 0; p4 < 8; ++p4) {
      const float4 uv = *reinterpret_cast<const float4*>(&W[ubase + p4*4]);
      const float u4[4] = {uv.x, uv.y, uv.z, uv.w};
#pragma unroll
      for (int pp = 0; pp < 4; ++pp) {
        const int p = p4*4 + pp;
        const float u = (p <= i0) ? u4[pp] : 0.f;
        const float2 tv = *reinterpret_cast<const float2*>(&Tbuf[p*36 + j0g]);
        g0 += u*tv.x; g1 += u*tv.y;
      }
    }
    __syncthreads();   // Tbuf reads done before next iter's overwrite
    {
      float2 wv; wv.x = -g0; wv.y = -g1;
      *reinterpret_cast<float2*>(&W[wb(32*I + i0) + 32*J + j0g]) = wv;
    }
    __syncthreads();   // W_IJ visible before next iteration's reads
  }

  // write back this block's G column-block (rows >= 32(J+1), cols [32J,32J+32))
  const int r0 = 32*(J + 1);
  const int nel = (256 - r0) * 32;
  for (int e = tid; e < nel; e += 512) {
    const int r = r0 + (e >> 5), c = 32*J + (e & 31);
    Wgk[wb(r) + c] = W[wb(r) + c];
  }
}

// ---------------------------------------------------------------------------
// K3: pack + t/bias.  [FROZEN]
// ---------------------------------------------------------------------------
__global__ __launch_bounds__(256, 1) void gmm_pack(
    unsigned short* __restrict__ planes, const float* __restrict__ mu,
    const float* __restrict__ pi, float* __restrict__ tvec,
    float* __restrict__ bias)
{
  __shared__ float W[WSZ];
  __shared__ float colbuf[D];
  __shared__ float red[256];
  const int k = blockIdx.x, tid = threadIdx.x;
  const float* Wgk = (const float*)(planes + (size_t)k*SLAB_SH);
  for (int idx = tid; idx < WSZ; idx += 256) W[idx] = Wgk[idx];
  colbuf[tid] = mu[k*D + tid];
  __syncthreads();

  {
    const int rb4 = wb(tid);
    float s = 0.0f;
    for (int p = 0; p <= tid; ++p) s += W[rb4 + p]*colbuf[p];
    tvec[k*D + tid] = s;
    red[tid] = s*s;
  }
  __syncthreads();
  for (int st = 128; st > 0; st >>= 1) { if (tid < st) red[tid] += red[tid+st]; __syncthreads(); }
  const float t2 = red[0];
  __syncthreads();
  red[tid] = logf(W[wb(tid) + tid]);
  __syncthreads();
  for (int st = 128; st > 0; st >>= 1) { if (tid < st) red[tid] += red[tid+st]; __syncthreads(); }
  if (tid == 0) bias[k] = logf(pi[k]) + red[0] - 0.5f*t2;
  __syncthreads();

  unsigned short* slab = planes + (size_t)k*SLAB_SH;
  for (int e = tid; e < SH_PER_CL; e += 256) {
    const int f = e >> 9, wrd = e & 511, l = wrd >> 3, j = wrd & 7;
    const int I = (f>=1)+(f>=2)+(f>=4)+(f>=6)+(f>=9)+(f>=12)+(f>=16)+(f>=20)
                +(f>=25)+(f>=30)+(f>=36)+(f>=42)+(f>=49)+(f>=56)+(f>=64);
    const int kc = f - frag_off(I);
    const int li = l & 15, hh = l >> 4;
    const int p = kc*32 + hh*8 + j, i2 = I*16 + li;
    const float g = (p <= i2) ? W[wb(i2) + p] : 0.0f;   // Gt[p][i] = G[i][p]
    const unsigned short hb = f2bf(g); const float hf = bf2f(hb);
    const float r1 = g - hf;
    const unsigned short lb = f2bf(r1); const float lf = bf2f(lb);
    const unsigned short rb = f2bf(r1 - lf);
    slab[e] = hb;
    slab[SH_PER_CL + e] = lb;
    slab[2*SH_PER_CL + e] = rb;
  }
}

// ---------------------------------------------------------------------------
// K4: MFMA scoring, split-2. LDS stages ONLY plane-h (73.7 KB -> 2 blocks/CU
// co-residency; cross-block overlap of staging and MFMA). Plane-l streams
// from global/L2 (feeds 2 of 6 chains). Same product set -> identical scores.
// ---------------------------------------------------------------------------
__global__ __launch_bounds__(512) void gmm_score_mfma(
    const float* __restrict__ x, const unsigned short* __restrict__ planes,
    const float* __restrict__ tvec, const float* __restrict__ bias,
    float* __restrict__ partq)
{
  __shared__ uint4 shb[4608];   // 73728 B: plane-h only
  const int tid = threadIdx.x, lane = tid & 63, w = tid >> 6;
  const int li = lane & 15, h = lane >> 4;
  const int kq = blockIdx.x & 7, ntile = blockIdx.x >> 3;   // XCD-local octants
  const int n0 = ntile*256 + w*32;

  short8 ah[2][8], al[2][8];
#pragma unroll
  for (int s = 0; s < 2; ++s) {
    const float* xr = x + (size_t)(n0 + s*16 + li)*D;
#pragma unroll
    for (int kc = 0; kc < 8; ++kc) {
      const float4 v0 = *reinterpret_cast<const float4*>(xr + kc*32 + h*8);
      const float4 v1 = *reinterpret_cast<const float4*>(xr + kc*32 + h*8 + 4);
      const float xv[8] = {v0.x, v0.y, v0.z, v0.w, v1.x, v1.y, v1.z, v1.w};
#pragma unroll
      for (int j = 0; j < 8; ++j) {
        const unsigned short hb = f2bf(xv[j]);
        ah[s][kc][j] = (short)hb;
        al[s][kc][j] = (short)f2bf(xv[j] - bf2f(hb));
      }
    }
  }

  float best0[4], sec0[4], best1[4], sec1[4];
  int bk0[4], bk1[4];
#pragma unroll
  for (int j = 0; j < 4; ++j) {
    best0[j] = -3.0e38f; sec0[j] = -3.0e38f; bk0[j] = 0;
    best1[j] = -3.0e38f; sec1[j] = -3.0e38f; bk1[j] = 0;
  }

  const unsigned short* shs = reinterpret_cast<const unsigned short*>(shb);

#pragma unroll 1
  for (int kk = 0; kk < 8; ++kk) {
    const int k = kq*8 + kk;
    __syncthreads();   // previous compute done before restage
    {
      const uint4* g4 = reinterpret_cast<const uint4*>(planes + (size_t)k*SLAB_SH);
#pragma unroll
      for (int it = 0; it < 9; ++it)
        shb[it*512 + tid] = g4[it*512 + tid];
    }
    __syncthreads();

    const unsigned short* blB = planes + (size_t)k*SLAB_SH + SH_PER_CL;
    const float* tk = tvec + k*D;
    float p0[4] = {0.f,0.f,0.f,0.f}, p1[4] = {0.f,0.f,0.f,0.f};
#pragma unroll
    for (int I = 0; I < 16; ++I) {
      const int fb = frag_off(I);
      const int kcnt = (I + 2) >> 1;
      f32x4 a0A = {0.f,0.f,0.f,0.f}, a0B = {0.f,0.f,0.f,0.f}, a0C = {0.f,0.f,0.f,0.f};
      f32x4 a1A = {0.f,0.f,0.f,0.f}, a1B = {0.f,0.f,0.f,0.f}, a1C = {0.f,0.f,0.f,0.f};
#pragma unroll
      for (int kc = 0; kc < kcnt; ++kc) {
        const int fo = (fb + kc)*512 + lane*8;
        const short8 bh = *reinterpret_cast<const short8*>(shs + fo);
        const short8 bl = *reinterpret_cast<const short8*>(blB + fo);
        a0A = __builtin_amdgcn_mfma_f32_16x16x32_bf16(ah[0][kc], bh, a0A, 0, 0, 0);
        a1A = __builtin_amdgcn_mfma_f32_16x16x32_bf16(ah[1][kc], bh, a1A, 0, 0, 0);
        a0B = __builtin_amdgcn_mfma_f32_16x16x32_bf16(al[0][kc], bh, a0B, 0, 0, 0);
        a1B = __builtin_amdgcn_mfma_f32_16x16x32_bf16(al[1][kc], bh, a1B, 0, 0, 0);
        a0C = __builtin_amdgcn_mfma_f32_16x16x32_bf16(ah[0][kc], bl, a0C, 0, 0, 0);
        a1C = __builtin_amdgcn_mfma_f32_16x16x32_bf16(ah[1][kc], bl, a1C, 0, 0, 0);
      }
      const float t = tk[I*16 + li];
#pragma unroll
      for (int j = 0; j < 4; ++j) {
        float y = a0A[j] + (a0B[j] + a0C[j]); p0[j] += y*(t - 0.5f*y);
        y = a1A[j] + (a1B[j] + a1C[j]);       p1[j] += y*(t - 0.5f*y);
      }
    }
#pragma unroll
    for (int mloc = 1; mloc < 16; mloc <<= 1) {
#pragma unroll
      for (int j = 0; j < 4; ++j) {
        p0[j] += __shfl_xor(p0[j], mloc, 64);
        p1[j] += __shfl_xor(p1[j], mloc, 64);
      }
    }
    const float bs = bias[k];
#pragma unroll
    for (int j = 0; j < 4; ++j) {
      const float s0v = bs + p0[j];
      if (s0v > best0[j]) { sec0[j] = best0[j]; best0[j] = s0v; bk0[j] = k; }
      else if (s0v > sec0[j]) sec0[j] = s0v;
      const float s1v = bs + p1[j];
      if (s1v > best1[j]) { sec1[j] = best1[j]; best1[j] = s1v; bk1[j] = k; }
      else if (s1v > sec1[j]) sec1[j] = s1v;
    }
  }

  if (li == 0) {
#pragma unroll
    for (int j = 0; j < 4; ++j) {
      const size_t r0 = ((size_t)kq*NPTS + n0 + h*4 + j)*3;
      partq[r0] = best0[j]; partq[r0+1] = __int_as_float(bk0[j]); partq[r0+2] = sec0[j];
      const size_t r1 = ((size_t)kq*NPTS + n0 + 16 + h*4 + j)*3;
      partq[r1] = best1[j]; partq[r1+1] = __int_as_float(bk1[j]); partq[r1+2] = sec1[j];
    }
  }
}

// ---------------------------------------------------------------------------
// K5: merge 8 octants; flag small-margin points.  [FROZEN]
// ---------------------------------------------------------------------------
__global__ __launch_bounds__(256) void gmm_merge(
    const float* __restrict__ partq, int* __restrict__ out,
    int* __restrict__ flaglist, int* __restrict__ flagcnt)
{
  const int n = blockIdx.x*256 + threadIdx.x;
  float b = -3.0e38f, s2 = -3.0e38f; int bk = 0;
#pragma unroll
  for (int q = 0; q < 8; ++q) {
    const size_t o = ((size_t)q*NPTS + n)*3;
    const float bq = partq[o];
    const int kq_ = __float_as_int(partq[o+1]);
    const float sq = partq[o+2];
    if (bq > b) { s2 = fmaxf(b, sq); b = bq; bk = kq_; }
    else        { s2 = fmaxf(s2, bq); }
  }
  out[n] = bk;
  if (b - s2 < 0.25f) {
    const int idx = atomicAdd(flagcnt, 1);
    flaglist[idx] = n;
  }
}

// ---------------------------------------------------------------------------
// K6: exact re-score, split-3, cluster-per-block, non-spilling (runtime
// I-loop + predicated static kc).  [FROZEN]
// ---------------------------------------------------------------------------
__global__ __launch_bounds__(256, 1) void gmm_escore(
    const float* __restrict__ x, const unsigned short* __restrict__ planes,
    const float* __restrict__ tvec, const float* __restrict__ bias,
    const int* __restrict__ flaglist, const int* __restrict__ flagcnt,
    float* __restrict__ escore)
{
  const int bid = blockIdx.x;
  const int k = bid & 63, gs = bid >> 6;
  const int tid = threadIdx.x, lane = tid & 63, w = tid >> 6;
  const int li = lane & 15, h = lane >> 4;
  const int cnt = *flagcnt;
  if (cnt == 0) return;

  const unsigned short* bhB = planes + (size_t)k*SLAB_SH;
  const unsigned short* blB = bhB + SH_PER_CL;
  const unsigned short* brB = bhB + 2*SH_PER_CL;
  const float* tk = tvec + k*D;
  const float bs = bias[k];

#pragma unroll 1
  for (int g = gs*4 + w; g*16 < cnt; g += 12) {
    const int slot = g*16 + li;
    const int row = (slot < cnt) ? flaglist[slot] : 0;

    short8 ah[8], al[8], ar[8];
    const float* xr = x + (size_t)row*D;
#pragma unroll
    for (int kc = 0; kc < 8; ++kc) {
      const float4 v0 = *reinterpret_cast<const float4*>(xr + kc*32 + h*8);
      const float4 v1 = *reinterpret_cast<const float4*>(xr + kc*32 + h*8 + 4);
      const float xv[8] = {v0.x, v0.y, v0.z, v0.w, v1.x, v1.y, v1.z, v1.w};
#pragma unroll
      for (int j = 0; j < 8; ++j) {
        const unsigned short hb = f2bf(xv[j]); const float hf = bf2f(hb);
        const float r1 = xv[j] - hf;
        const unsigned short lb = f2bf(r1); const float lf = bf2f(lb);
        ah[kc][j] = (short)hb; al[kc][j] = (short)lb; ar[kc][j] = (short)f2bf(r1 - lf);
      }
    }

    float p[4] = {0.f,0.f,0.f,0.f};
#pragma unroll 1
    for (int I = 0; I < 16; ++I) {
      const int fb = frag_off(I);
      const int kcnt = (I + 2) >> 1;
      f32x4 accA = {0.f,0.f,0.f,0.f}, accB = {0.f,0.f,0.f,0.f};
#pragma unroll
      for (int kc = 0; kc < 8; ++kc) {
        if (kc < kcnt) {   // wave-uniform: s_cbranch skip, no divergence
          const int fo = (fb + kc)*512 + lane*8;
          const short8 bh = *reinterpret_cast<const short8*>(bhB + fo);
          const short8 bl = *reinterpret_cast<const short8*>(blB + fo);
          const short8 br = *reinterpret_cast<const short8*>(brB + fo);
          accA = __builtin_amdgcn_mfma_f32_16x16x32_bf16(ah[kc], bh, accA, 0, 0, 0);
          accB = __builtin_amdgcn_mfma_f32_16x16x32_bf16(al[kc], bh, accB, 0, 0, 0);
          accB = __builtin_amdgcn_mfma_f32_16x16x32_bf16(ar[kc], bh, accB, 0, 0, 0);
          accB = __builtin_amdgcn_mfma_f32_16x16x32_bf16(ah[kc], bl, accB, 0, 0, 0);
          accB = __builtin_amdgcn_mfma_f32_16x16x32_bf16(al[kc], bl, accB, 0, 0, 0);
          accB = __builtin_amdgcn_mfma_f32_16x16x32_bf16(ah[kc], br, accB, 0, 0, 0);
        }
      }
      const float t = tk[I*16 + li];
#pragma unroll
      for (int j = 0; j < 4; ++j) {
        const float y = accA[j] + accB[j];
        p[j] += y*(t - 0.5f*y);
      }
    }
#pragma unroll
    for (int mloc = 1; mloc < 16; mloc <<= 1) {
#pragma unroll
      for (int j = 0; j < 4; ++j) p[j] += __shfl_xor(p[j], mloc, 64);
    }
    if (li == 0) {
#pragma unroll
      for (int j = 0; j < 4; ++j) {
        const int slot2 = g*16 + h*4 + j;
        if (slot2 < cnt) escore[(size_t)k*NPTS + slot2] = bs + p[j];
      }
    }
  }
}

// ---------------------------------------------------------------------------
// K7: exact merge.  [FROZEN]
// ---------------------------------------------------------------------------
__global__ __launch_bounds__(256) void gmm_emerge(
    const float* __restrict__ escore, const int* __restrict__ flaglist,
    const int* __restrict__ flagcnt, int* __restrict__ out)
{
  const int cnt = *flagcnt;
  const int s = blockIdx.x*256 + threadIdx.x;
  if (s >= cnt) return;
  float b = escore[s]; int bk = 0;
#pragma unroll 1
  for (int k = 1; k < KC; ++k) {
    const float v = escore[(size_t)k*NPTS + s];
    if (v > b) { b = v; bk = k; }
  }
  out[flaglist[s]] = bk;
}

extern "C" void kernel_launch(void* const* d_in, const int* in_sizes, int n_in,
                              void* d_out, int out_size, void* d_ws, size_t ws_size,
                              hipStream_t stream)
{
  const float* x   = (const float*)d_in[0];   // (8192, 256)
  const float* mu  = (const float*)d_in[1];   // (64, 256)
  const float* var = (const float*)d_in[2];   // (64, 256, 256)
  const float* pi  = (const float*)d_in[3];   // (64,)

  char* ws = (char*)d_ws;
  unsigned short* planes = (unsigned short*)ws;                      // 64 cluster slabs, 14.16 MB
  float* tvec = (float*)(ws + KC*SLAB_SH*sizeof(unsigned short));    // 64 KB
  float* bias = tvec + KC*D;                                         // 64 floats (pad to 256)
  int* flaglist = (int*)(bias + 256);                                // 8192 ints
  int* flagcnt = flaglist + NPTS;                                    // 1 int (pad 64)
  float* partq = (float*)(flagcnt + 64);                             // 8*8192*3 floats
  float* escore = partq;                                             // aliases partq (dead after merge); 64*8192 floats
  int* out = (int*)d_out;

  gmm_chol<<<KC, 512, 0, stream>>>(var, planes);
  gmm_inv3<<<7*KC, 512, 0, stream>>>(planes);
  gmm_pack<<<KC, 256, 0, stream>>>(planes, mu, pi, tvec, bias);
  gmm_score_mfma<<<256, 512, 0, stream>>>(x, planes, tvec, bias, partq);
  hipMemsetAsync(flagcnt, 0, sizeof(int), stream);
  gmm_merge<<<NPTS/256, 256, 0, stream>>>(partq, out, flaglist, flagcnt);
  gmm_escore<<<3*KC, 256, 0, stream>>>(x, planes, tvec, bias, flaglist, flagcnt, escore);
  gmm_emerge<<<NPTS/256, 256, 0, stream>>>(escore, flaglist, flagcnt, out);
}

// Round 25
// 667.903 us; speedup vs baseline: 1.0601x; 1.0601x over previous
//
#include <hip/hip_runtime.h>
#include <math.h>

#define D 256
#define KC 64
#define NPTS 8192
#define TRI ((D*(D+1))/2)

#define WSZ 33920             // 16B-aligned, cumulative 16B/row-staggered packed triangle
#define FR_PER_CL 72          // triangular 16x16x32 fragments per cluster
#define SH_PER_CL (FR_PER_CL*512)           // shorts per cluster per plane
#define SLAB_SH ((size_t)(3*SH_PER_CL))     // shorts per cluster slab (3 planes)

typedef __attribute__((ext_vector_type(8))) short short8;
typedef __attribute__((ext_vector_type(4))) float f32x4;

// row base: 16B-aligned, CUMULATIVE 16B-per-row stagger (injective; bases walk
// the 128B bank period)
__device__ __forceinline__ int wb(int r) {
  return ((r*(r+1)/2 + 3) & ~3) + (r << 2);
}
__device__ __forceinline__ unsigned short f2bf(float f) {                   // RNE float->bf16 bits
  unsigned u = __float_as_uint(f);
  u = (u + 0x7fffu + ((u >> 16) & 1u)) >> 16;
  return (unsigned short)u;
}
__device__ __forceinline__ float bf2f(unsigned short s) { return __uint_as_float(((unsigned)s) << 16); }
__device__ __forceinline__ float rdlane(float v, int l) {
  return __uint_as_float(__builtin_amdgcn_readlane(__float_as_uint(v), l));
}
__device__ __forceinline__ int frag_off(int I) { int a = I >> 1; return (I & 1) ? (a+1)*(a+1) : a*(a+1); }

// ---------------------------------------------------------------------------
// K1: blocked Cholesky (B=32 panels), 512 threads (proven non-spilling:
// VGPR 128): serial register diag core (U on diag), TRSM (2 threads/row),
// SYRK. Writes L-triangle (U on diag blocks) to slab head.  [FROZEN]
// ---------------------------------------------------------------------------
__global__ __launch_bounds__(512, 1) void gmm_chol(
    const float* __restrict__ var, unsigned short* __restrict__ planes)
{
  __shared__ float W[WSZ];
  __shared__ float Tbuf[32*36];

  const int k = blockIdx.x, tid = threadIdx.x;
  const int lane = tid & 63, wid = tid >> 6;
  const float* A = var + (size_t)k*D*D;

  for (int idx = tid; idx < TRI; idx += 512) {
    int i = (int)((sqrtf(8.0f*(float)idx + 1.0f) - 1.0f)*0.5f);
    while ((i+1)*(i+2)/2 <= idx) ++i;
    while (i*(i+1)/2 > idx) --i;
    const int p = idx - i*(i+1)/2;
    W[wb(i) + p] = A[i*D + p];
  }
  __syncthreads();

#pragma unroll 1
  for (int jb = 0; jb < 8; ++jb) {
    const int c0 = jb*32, c1 = c0 + 32, m = 256 - c1;

    if (wid == 0 && lane < 32) {
      const int rbase = wb(c0 + lane) + c0;
      float Arow[32];
#pragma unroll
      for (int p = 0; p < 32; ++p) Arow[p] = W[rbase + p];   // p>lane: garbage, never escapes

      float mydinv = 0.0f;
#pragma unroll
      for (int j = 0; j < 32; ++j) {
        const float dj = sqrtf(rdlane(Arow[j], j));
        const float dinv = 1.0f / dj;
        const float c = Arow[j] * dinv;
        Arow[j] = (lane == j) ? dj : c;
        mydinv = (lane == j) ? dinv : mydinv;
#pragma unroll
        for (int p = j + 1; p < 32; ++p) {
          const float cp = rdlane(c, p);
          Arow[p] -= c * cp;
        }
      }

      // G11 = inv(L11), forward substitution fused in place
#pragma unroll
      for (int p = 0; p < 32; ++p) {
        const float lp = (lane > p) ? Arow[p] : 0.0f;
#pragma unroll
        for (int j = 0; j < p; ++j) {
          const float fin = (0.0f - Arow[j]) * mydinv;
          Arow[j] = (lane == p) ? fin : Arow[j];
        }
        Arow[p] = (lane == p) ? mydinv : Arow[p];
#pragma unroll
        for (int j = 0; j < p; ++j) {
          const float gpj = rdlane(Arow[j], p);
          Arow[j] += lp * gpj;
        }
        const float gpp = rdlane(Arow[p], p);
        Arow[p] = (lane > p) ? (lp * gpp) : Arow[p];
      }

#pragma unroll
      for (int j = 0; j < 32; ++j) {
        if (j <= lane) W[rbase + j] = Arow[j];
        Tbuf[lane*36 + j] = (j <= lane) ? Arow[j] : 0.0f;
      }
    }
    __syncthreads();

    // TRSM: 2 threads/row; preload rows (b128), barrier, compute+write
    {
      const int m2 = 2*m;
      const int r = tid >> 1, jh = tid & 1;
      const int rb = wb(c1 + r) + c0;
      float row[32];
      if (tid < m2) {
#pragma unroll
        for (int p4 = 0; p4 < 8; ++p4) {
          const float4 v = *reinterpret_cast<const float4*>(&W[rb + p4*4]);
          row[p4*4+0] = v.x; row[p4*4+1] = v.y; row[p4*4+2] = v.z; row[p4*4+3] = v.w;
        }
      }
      __syncthreads();
      if (tid < m2) {
        const int j0 = jh*16;
#pragma unroll 1
        for (int j = j0; j < j0 + 16; ++j) {
          const float* up = &Tbuf[j*36];
          float s0 = 0.f, s1 = 0.f, s2 = 0.f, s3 = 0.f;
#pragma unroll
          for (int p4 = 0; p4 < 8; ++p4) {
            const float4 u = *reinterpret_cast<const float4*>(&up[p4*4]);
            s0 += row[p4*4+0]*u.x; s1 += row[p4*4+1]*u.y;
            s2 += row[p4*4+2]*u.z; s3 += row[p4*4+3]*u.w;
          }
          W[rb + j] = (s0 + s1) + (s2 + s3);
        }
      }
    }
    __syncthreads();

    // SYRK: trailing triangle -= L21*L21^T, b128 reads along p
    if (m > 0) {
      const int nt = m >> 2, ntri = nt*(nt+1)/2;
      for (int tau = tid; tau < ntri; tau += 512) {
        int ti = (int)((sqrtf(8.0f*(float)tau + 1.0f) - 1.0f)*0.5f);
        while ((ti+1)*(ti+2)/2 <= tau) ++ti;
        while (ti*(ti+1)/2 > tau) --ti;
        const int tl = tau - ti*(ti+1)/2;
        const int i0 = c1 + ti*4, l0 = c1 + tl*4;
        const int ib[4] = {wb(i0)+c0, wb(i0+1)+c0, wb(i0+2)+c0, wb(i0+3)+c0};
        const int lb[4] = {wb(l0)+c0, wb(l0+1)+c0, wb(l0+2)+c0, wb(l0+3)+c0};
        float acc[4][4];
#pragma unroll
        for (int a = 0; a < 4; ++a)
#pragma unroll
          for (int b = 0; b < 4; ++b) acc[a][b] = 0.0f;
#pragma unroll
        for (int p4 = 0; p4 < 8; ++p4) {
          float4 av[4], bv[4];
#pragma unroll
          for (int a = 0; a < 4; ++a) av[a] = *reinterpret_cast<const float4*>(&W[ib[a] + p4*4]);
#pragma unroll
          for (int b = 0; b < 4; ++b) bv[b] = *reinterpret_cast<const float4*>(&W[lb[b] + p4*4]);
#pragma unroll
          for (int a = 0; a < 4; ++a)
#pragma unroll
            for (int b = 0; b < 4; ++b)
              acc[a][b] += av[a].x*bv[b].x + av[a].y*bv[b].y + av[a].z*bv[b].z + av[a].w*bv[b].w;
        }
#pragma unroll
        for (int a = 0; a < 4; ++a)
#pragma unroll
          for (int b = 0; b < 4; ++b) {
            const int rr = i0 + a, cc = l0 + b;
            if (cc <= rr) W[wb(rr) + cc] -= acc[a][b];
          }
      }
    }
    __syncthreads();
  }

  float* Wgk = (float*)(planes + (size_t)k*SLAB_SH);
  for (int idx = tid; idx < WSZ; idx += 512) Wgk[idx] = W[idx];
}

// ---------------------------------------------------------------------------
// K2: column-parallel triangular inversion, 7 blocks/cluster (one J each;
// J=7 has no off-diag work). Each block loads only rows >= 32J, runs the
// in-place column recurrence for J, writes back rows >= 32(J+1) of
// column-block J (disjoint across blocks).
// ---------------------------------------------------------------------------
__global__ __launch_bounds__(512, 1) void gmm_inv3(unsigned short* __restrict__ planes)
{
  __shared__ float W[WSZ];
  __shared__ float Tbuf[32*36];

  const int b = blockIdx.x, k = b/7, J = b - 7*(b/7);
  const int tid = threadIdx.x;
  float* Wgk = (float*)(planes + (size_t)k*SLAB_SH);
  const int base = wb(32*J);           // 16B-aligned; rows >= 32J live at [base, WSZ)
  for (int idx = base + tid; idx < WSZ; idx += 512) W[idx] = Wgk[idx];
  __syncthreads();

  const int i0 = tid >> 4;
  const int j0g = (tid & 15) * 2;

#pragma unroll 1
  for (int I = J + 1; I < 8; ++I) {
    float acc0 = 0.f, acc1 = 0.f;
    for (int K = J; K < I; ++K) {
      const int abase = wb(32*I + i0) + 32*K;
      const int brow = 32*K, bcol = 32*J + j0g;
      const bool dK = (K == J);
#pragma unroll
      for (int p4 = 0; p4 < 8; ++p4) {
        const float4 av = *reinterpret_cast<const float4*>(&W[abase + p4*4]);
        const float a4[4] = {av.x, av.y, av.z, av.w};
#pragma unroll
        for (int pp = 0; pp < 4; ++pp) {
          const int p = p4*4 + pp;
          const float2 bv = *reinterpret_cast<const float2*>(&W[wb(brow + p) + bcol]);
          float b0 = bv.x, b1 = bv.y;
          if (dK) { if (j0g > p) b0 = 0.f; if (j0g + 1 > p) b1 = 0.f; }
          acc0 += a4[pp]*b0; acc1 += a4[pp]*b1;
        }
      }
    }
    Tbuf[i0*36 + j0g] = acc0;
    Tbuf[i0*36 + j0g + 1] = acc1;
    __syncthreads();

    float g0 = 0.f, g1 = 0.f;
    const int ubase = wb(32*I + i0) + 32*I;
#pragma unroll
    for (int p4 = 0; p4 < 8; ++p4) {
      const float4 uv = *reinterpret_cast<const float4*>(&W[ubase + p4*4]);
      const float u4[4] = {uv.x, uv.y, uv.z, uv.w};
#pragma unroll
      for (int pp = 0; pp < 4; ++pp) {
        const int p = p4*4 + pp;
        const float u = (p <= i0) ? u4[pp] : 0.f;
        const float2 tv = *reinterpret_cast<const float2*>(&Tbuf[p*36 + j0g]);
        g0 += u*tv.x; g1 += u*tv.y;
      }
    }
    __syncthreads();   // Tbuf reads done before next iter's overwrite
    {
      float2 wv; wv.x = -g0; wv.y = -g1;
      *reinterpret_cast<float2*>(&W[wb(32*I + i0) + 32*J + j0g]) = wv;
    }
    __syncthreads();   // W_IJ visible before next iteration's reads
  }

  // write back this block's G column-block (rows >= 32(J+1), cols [32J,32J+32))
  const int r0 = 32*(J + 1);
  const int nel = (256 - r0) * 32;
  for (int e = tid; e < nel; e += 512) {
    const int r = r0 + (e >> 5), c = 32*J + (e & 31);
    Wgk[wb(r) + c] = W[wb(r) + c];
  }
}

// ---------------------------------------------------------------------------
// K3: pack + t/bias.  [FROZEN]
// ---------------------------------------------------------------------------
__global__ __launch_bounds__(256, 1) void gmm_pack(
    unsigned short* __restrict__ planes, const float* __restrict__ mu,
    const float* __restrict__ pi, float* __restrict__ tvec,
    float* __restrict__ bias)
{
  __shared__ float W[WSZ];
  __shared__ float colbuf[D];
  __shared__ float red[256];
  const int k = blockIdx.x, tid = threadIdx.x;
  const float* Wgk = (const float*)(planes + (size_t)k*SLAB_SH);
  for (int idx = tid; idx < WSZ; idx += 256) W[idx] = Wgk[idx];
  colbuf[tid] = mu[k*D + tid];
  __syncthreads();

  {
    const int rb4 = wb(tid);
    float s = 0.0f;
    for (int p = 0; p <= tid; ++p) s += W[rb4 + p]*colbuf[p];
    tvec[k*D + tid] = s;
    red[tid] = s*s;
  }
  __syncthreads();
  for (int st = 128; st > 0; st >>= 1) { if (tid < st) red[tid] += red[tid+st]; __syncthreads(); }
  const float t2 = red[0];
  __syncthreads();
  red[tid] = logf(W[wb(tid) + tid]);
  __syncthreads();
  for (int st = 128; st > 0; st >>= 1) { if (tid < st) red[tid] += red[tid+st]; __syncthreads(); }
  if (tid == 0) bias[k] = logf(pi[k]) + red[0] - 0.5f*t2;
  __syncthreads();

  unsigned short* slab = planes + (size_t)k*SLAB_SH;
  for (int e = tid; e < SH_PER_CL; e += 256) {
    const int f = e >> 9, wrd = e & 511, l = wrd >> 3, j = wrd & 7;
    const int I = (f>=1)+(f>=2)+(f>=4)+(f>=6)+(f>=9)+(f>=12)+(f>=16)+(f>=20)
                +(f>=25)+(f>=30)+(f>=36)+(f>=42)+(f>=49)+(f>=56)+(f>=64);
    const int kc = f - frag_off(I);
    const int li = l & 15, hh = l >> 4;
    const int p = kc*32 + hh*8 + j, i2 = I*16 + li;
    const float g = (p <= i2) ? W[wb(i2) + p] : 0.0f;   // Gt[p][i] = G[i][p]
    const unsigned short hb = f2bf(g); const float hf = bf2f(hb);
    const float r1 = g - hf;
    const unsigned short lb = f2bf(r1); const float lf = bf2f(lb);
    const unsigned short rb = f2bf(r1 - lf);
    slab[e] = hb;
    slab[SH_PER_CL + e] = lb;
    slab[2*SH_PER_CL + e] = rb;
  }
}

// ---------------------------------------------------------------------------
// K4: MFMA scoring, split-2, LDS-staged B (h+l planes, 147 KB — round-23
// verified config), XCD-local block mapping.
// ---------------------------------------------------------------------------
__global__ __launch_bounds__(512, 1) void gmm_score_mfma(
    const float* __restrict__ x, const unsigned short* __restrict__ planes,
    const float* __restrict__ tvec, const float* __restrict__ bias,
    float* __restrict__ partq)
{
  __shared__ uint4 shb[9216];   // 147456 B: plane-h + plane-l
  const int tid = threadIdx.x, lane = tid & 63, w = tid >> 6;
  const int li = lane & 15, h = lane >> 4;
  const int kq = blockIdx.x & 7, ntile = blockIdx.x >> 3;   // XCD-local octants
  const int n0 = ntile*256 + w*32;

  short8 ah[2][8], al[2][8];
#pragma unroll
  for (int s = 0; s < 2; ++s) {
    const float* xr = x + (size_t)(n0 + s*16 + li)*D;
#pragma unroll
    for (int kc = 0; kc < 8; ++kc) {
      const float4 v0 = *reinterpret_cast<const float4*>(xr + kc*32 + h*8);
      const float4 v1 = *reinterpret_cast<const float4*>(xr + kc*32 + h*8 + 4);
      const float xv[8] = {v0.x, v0.y, v0.z, v0.w, v1.x, v1.y, v1.z, v1.w};
#pragma unroll
      for (int j = 0; j < 8; ++j) {
        const unsigned short hb = f2bf(xv[j]);
        ah[s][kc][j] = (short)hb;
        al[s][kc][j] = (short)f2bf(xv[j] - bf2f(hb));
      }
    }
  }

  float best0[4], sec0[4], best1[4], sec1[4];
  int bk0[4], bk1[4];
#pragma unroll
  for (int j = 0; j < 4; ++j) {
    best0[j] = -3.0e38f; sec0[j] = -3.0e38f; bk0[j] = 0;
    best1[j] = -3.0e38f; sec1[j] = -3.0e38f; bk1[j] = 0;
  }

  const unsigned short* shs = reinterpret_cast<const unsigned short*>(shb);

#pragma unroll 1
  for (int kk = 0; kk < 8; ++kk) {
    const int k = kq*8 + kk;
    __syncthreads();   // previous compute done before restage
    {
      const uint4* g4 = reinterpret_cast<const uint4*>(planes + (size_t)k*SLAB_SH);
#pragma unroll
      for (int it = 0; it < 18; ++it)
        shb[it*512 + tid] = g4[it*512 + tid];
    }
    __syncthreads();

    const float* tk = tvec + k*D;
    float p0[4] = {0.f,0.f,0.f,0.f}, p1[4] = {0.f,0.f,0.f,0.f};
#pragma unroll
    for (int I = 0; I < 16; ++I) {
      const int fb = frag_off(I);
      const int kcnt = (I + 2) >> 1;
      f32x4 a0A = {0.f,0.f,0.f,0.f}, a0B = {0.f,0.f,0.f,0.f}, a0C = {0.f,0.f,0.f,0.f};
      f32x4 a1A = {0.f,0.f,0.f,0.f}, a1B = {0.f,0.f,0.f,0.f}, a1C = {0.f,0.f,0.f,0.f};
#pragma unroll
      for (int kc = 0; kc < kcnt; ++kc) {
        const int fo = (fb + kc)*512 + lane*8;
        const short8 bh = *reinterpret_cast<const short8*>(shs + fo);
        const short8 bl = *reinterpret_cast<const short8*>(shs + 36864 + fo);
        a0A = __builtin_amdgcn_mfma_f32_16x16x32_bf16(ah[0][kc], bh, a0A, 0, 0, 0);
        a1A = __builtin_amdgcn_mfma_f32_16x16x32_bf16(ah[1][kc], bh, a1A, 0, 0, 0);
        a0B = __builtin_amdgcn_mfma_f32_16x16x32_bf16(al[0][kc], bh, a0B, 0, 0, 0);
        a1B = __builtin_amdgcn_mfma_f32_16x16x32_bf16(al[1][kc], bh, a1B, 0, 0, 0);
        a0C = __builtin_amdgcn_mfma_f32_16x16x32_bf16(ah[0][kc], bl, a0C, 0, 0, 0);
        a1C = __builtin_amdgcn_mfma_f32_16x16x32_bf16(ah[1][kc], bl, a1C, 0, 0, 0);
      }
      const float t = tk[I*16 + li];
#pragma unroll
      for (int j = 0; j < 4; ++j) {
        float y = a0A[j] + (a0B[j] + a0C[j]); p0[j] += y*(t - 0.5f*y);
        y = a1A[j] + (a1B[j] + a1C[j]);       p1[j] += y*(t - 0.5f*y);
      }
    }
#pragma unroll
    for (int mloc = 1; mloc < 16; mloc <<= 1) {
#pragma unroll
      for (int j = 0; j < 4; ++j) {
        p0[j] += __shfl_xor(p0[j], mloc, 64);
        p1[j] += __shfl_xor(p1[j], mloc, 64);
      }
    }
    const float bs = bias[k];
#pragma unroll
    for (int j = 0; j < 4; ++j) {
      const float s0v = bs + p0[j];
      if (s0v > best0[j]) { sec0[j] = best0[j]; best0[j] = s0v; bk0[j] = k; }
      else if (s0v > sec0[j]) sec0[j] = s0v;
      const float s1v = bs + p1[j];
      if (s1v > best1[j]) { sec1[j] = best1[j]; best1[j] = s1v; bk1[j] = k; }
      else if (s1v > sec1[j]) sec1[j] = s1v;
    }
  }

  if (li == 0) {
#pragma unroll
    for (int j = 0; j < 4; ++j) {
      const size_t r0 = ((size_t)kq*NPTS + n0 + h*4 + j)*3;
      partq[r0] = best0[j]; partq[r0+1] = __int_as_float(bk0[j]); partq[r0+2] = sec0[j];
      const size_t r1 = ((size_t)kq*NPTS + n0 + 16 + h*4 + j)*3;
      partq[r1] = best1[j]; partq[r1+1] = __int_as_float(bk1[j]); partq[r1+2] = sec1[j];
    }
  }
}

// ---------------------------------------------------------------------------
// K5: merge 8 octants; flag small-margin points.  [FROZEN]
// ---------------------------------------------------------------------------
__global__ __launch_bounds__(256) void gmm_merge(
    const float* __restrict__ partq, int* __restrict__ out,
    int* __restrict__ flaglist, int* __restrict__ flagcnt)
{
  const int n = blockIdx.x*256 + threadIdx.x;
  float b = -3.0e38f, s2 = -3.0e38f; int bk = 0;
#pragma unroll
  for (int q = 0; q < 8; ++q) {
    const size_t o = ((size_t)q*NPTS + n)*3;
    const float bq = partq[o];
    const int kq_ = __float_as_int(partq[o+1]);
    const float sq = partq[o+2];
    if (bq > b) { s2 = fmaxf(b, sq); b = bq; bk = kq_; }
    else        { s2 = fmaxf(s2, bq); }
  }
  out[n] = bk;
  if (b - s2 < 0.25f) {
    const int idx = atomicAdd(flagcnt, 1);
    flaglist[idx] = n;
  }
}

// ---------------------------------------------------------------------------
// K6: exact re-score, split-3, cluster-per-block, non-spilling (runtime
// I-loop + predicated static kc).  [FROZEN]
// ---------------------------------------------------------------------------
__global__ __launch_bounds__(256, 1) void gmm_escore(
    const float* __restrict__ x, const unsigned short* __restrict__ planes,
    const float* __restrict__ tvec, const float* __restrict__ bias,
    const int* __restrict__ flaglist, const int* __restrict__ flagcnt,
    float* __restrict__ escore)
{
  const int bid = blockIdx.x;
  const int k = bid & 63, gs = bid >> 6;
  const int tid = threadIdx.x, lane = tid & 63, w = tid >> 6;
  const int li = lane & 15, h = lane >> 4;
  const int cnt = *flagcnt;
  if (cnt == 0) return;

  const unsigned short* bhB = planes + (size_t)k*SLAB_SH;
  const unsigned short* blB = bhB + SH_PER_CL;
  const unsigned short* brB = bhB + 2*SH_PER_CL;
  const float* tk = tvec + k*D;
  const float bs = bias[k];

#pragma unroll 1
  for (int g = gs*4 + w; g*16 < cnt; g += 12) {
    const int slot = g*16 + li;
    const int row = (slot < cnt) ? flaglist[slot] : 0;

    short8 ah[8], al[8], ar[8];
    const float* xr = x + (size_t)row*D;
#pragma unroll
    for (int kc = 0; kc < 8; ++kc) {
      const float4 v0 = *reinterpret_cast<const float4*>(xr + kc*32 + h*8);
      const float4 v1 = *reinterpret_cast<const float4*>(xr + kc*32 + h*8 + 4);
      const float xv[8] = {v0.x, v0.y, v0.z, v0.w, v1.x, v1.y, v1.z, v1.w};
#pragma unroll
      for (int j = 0; j < 8; ++j) {
        const unsigned short hb = f2bf(xv[j]); const float hf = bf2f(hb);
        const float r1 = xv[j] - hf;
        const unsigned short lb = f2bf(r1); const float lf = bf2f(lb);
        ah[kc][j] = (short)hb; al[kc][j] = (short)lb; ar[kc][j] = (short)f2bf(r1 - lf);
      }
    }

    float p[4] = {0.f,0.f,0.f,0.f};
#pragma unroll 1
    for (int I = 0; I < 16; ++I) {
      const int fb = frag_off(I);
      const int kcnt = (I + 2) >> 1;
      f32x4 accA = {0.f,0.f,0.f,0.f}, accB = {0.f,0.f,0.f,0.f};
#pragma unroll
      for (int kc = 0; kc < 8; ++kc) {
        if (kc < kcnt) {   // wave-uniform: s_cbranch skip, no divergence
          const int fo = (fb + kc)*512 + lane*8;
          const short8 bh = *reinterpret_cast<const short8*>(bhB + fo);
          const short8 bl = *reinterpret_cast<const short8*>(blB + fo);
          const short8 br = *reinterpret_cast<const short8*>(brB + fo);
          accA = __builtin_amdgcn_mfma_f32_16x16x32_bf16(ah[kc], bh, accA, 0, 0, 0);
          accB = __builtin_amdgcn_mfma_f32_16x16x32_bf16(al[kc], bh, accB, 0, 0, 0);
          accB = __builtin_amdgcn_mfma_f32_16x16x32_bf16(ar[kc], bh, accB, 0, 0, 0);
          accB = __builtin_amdgcn_mfma_f32_16x16x32_bf16(ah[kc], bl, accB, 0, 0, 0);
          accB = __builtin_amdgcn_mfma_f32_16x16x32_bf16(al[kc], bl, accB, 0, 0, 0);
          accB = __builtin_amdgcn_mfma_f32_16x16x32_bf16(ah[kc], br, accB, 0, 0, 0);
        }
      }
      const float t = tk[I*16 + li];
#pragma unroll
      for (int j = 0; j < 4; ++j) {
        const float y = accA[j] + accB[j];
        p[j] += y*(t - 0.5f*y);
      }
    }
#pragma unroll
    for (int mloc = 1; mloc < 16; mloc <<= 1) {
#pragma unroll
      for (int j = 0; j < 4; ++j) p[j] += __shfl_xor(p[j], mloc, 64);
    }
    if (li == 0) {
#pragma unroll
      for (int j = 0; j < 4; ++j) {
        const int slot2 = g*16 + h*4 + j;
        if (slot2 < cnt) escore[(size_t)k*NPTS + slot2] = bs + p[j];
      }
    }
  }
}

// ---------------------------------------------------------------------------
// K7: exact merge.  [FROZEN]
// ---------------------------------------------------------------------------
__global__ __launch_bounds__(256) void gmm_emerge(
    const float* __restrict__ escore, const int* __restrict__ flaglist,
    const int* __restrict__ flagcnt, int* __restrict__ out)
{
  const int cnt = *flagcnt;
  const int s = blockIdx.x*256 + threadIdx.x;
  if (s >= cnt) return;
  float b = escore[s]; int bk = 0;
#pragma unroll 1
  for (int k = 1; k < KC; ++k) {
    const float v = escore[(size_t)k*NPTS + s];
    if (v > b) { b = v; bk = k; }
  }
  out[flaglist[s]] = bk;
}

extern "C" void kernel_launch(void* const* d_in, const int* in_sizes, int n_in,
                              void* d_out, int out_size, void* d_ws, size_t ws_size,
                              hipStream_t stream)
{
  const float* x   = (const float*)d_in[0];   // (8192, 256)
  const float* mu  = (const float*)d_in[1];   // (64, 256)
  const float* var = (const float*)d_in[2];   // (64, 256, 256)
  const float* pi  = (const float*)d_in[3];   // (64,)

  char* ws = (char*)d_ws;
  unsigned short* planes = (unsigned short*)ws;                      // 64 cluster slabs, 14.16 MB
  float* tvec = (float*)(ws + KC*SLAB_SH*sizeof(unsigned short));    // 64 KB
  float* bias = tvec + KC*D;                                         // 64 floats (pad to 256)
  int* flaglist = (int*)(bias + 256);                                // 8192 ints
  int* flagcnt = flaglist + NPTS;                                    // 1 int (pad 64)
  float* partq = (float*)(flagcnt + 64);                             // 8*8192*3 floats
  float* escore = partq;                                             // aliases partq (dead after merge); 64*8192 floats
  int* out = (int*)d_out;

  gmm_chol<<<KC, 512, 0, stream>>>(var, planes);
  gmm_inv3<<<7*KC, 512, 0, stream>>>(planes);
  gmm_pack<<<KC, 256, 0, stream>>>(planes, mu, pi, tvec, bias);
  gmm_score_mfma<<<256, 512, 0, stream>>>(x, planes, tvec, bias, partq);
  hipMemsetAsync(flagcnt, 0, sizeof(int), stream);
  gmm_merge<<<NPTS/256, 256, 0, stream>>>(partq, out, flaglist, flagcnt);
  gmm_escore<<<3*KC, 256, 0, stream>>>(x, planes, tvec, bias, flaglist, flagcnt, escore);
  gmm_emerge<<<NPTS/256, 256, 0, stream>>>(escore, flaglist, flagcnt, out);
}

// Round 26
// 662.245 us; speedup vs baseline: 1.0692x; 1.0085x over previous
//
#include <hip/hip_runtime.h>
#include <math.h>

#define D 256
#define KC 64
#define NPTS 8192
#define TRI ((D*(D+1))/2)

#define WSZ 33920             // 16B-aligned, cumulative 16B/row-staggered packed triangle
#define FR_PER_CL 72          // triangular 16x16x32 fragments per cluster
#define SH_PER_CL (FR_PER_CL*512)           // shorts per cluster per plane
#define SLAB_SH ((size_t)(3*SH_PER_CL))     // shorts per cluster slab (3 planes)

typedef __attribute__((ext_vector_type(8))) short short8;
typedef __attribute__((ext_vector_type(4))) float f32x4;

// row base: 16B-aligned, CUMULATIVE 16B-per-row stagger (injective; bases walk
// the 128B bank period)
__device__ __forceinline__ int wb(int r) {
  return ((r*(r+1)/2 + 3) & ~3) + (r << 2);
}
__device__ __forceinline__ unsigned short f2bf(float f) {                   // RNE float->bf16 bits
  unsigned u = __float_as_uint(f);
  u = (u + 0x7fffu + ((u >> 16) & 1u)) >> 16;
  return (unsigned short)u;
}
__device__ __forceinline__ float bf2f(unsigned short s) { return __uint_as_float(((unsigned)s) << 16); }
__device__ __forceinline__ float rdlane(float v, int l) {
  return __uint_as_float(__builtin_amdgcn_readlane(__float_as_uint(v), l));
}
__device__ __forceinline__ int frag_off(int I) { int a = I >> 1; return (I & 1) ? (a+1)*(a+1) : a*(a+1); }

// ---------------------------------------------------------------------------
// K1: blocked Cholesky (B=32 panels), 512 threads (proven non-spilling:
// VGPR 128): serial register diag core (U on diag), TRSM (2 threads/row),
// SYRK. Writes L-triangle (U on diag blocks) to slab head.  [FROZEN]
// ---------------------------------------------------------------------------
__global__ __launch_bounds__(512, 1) void gmm_chol(
    const float* __restrict__ var, unsigned short* __restrict__ planes)
{
  __shared__ float W[WSZ];
  __shared__ float Tbuf[32*36];

  const int k = blockIdx.x, tid = threadIdx.x;
  const int lane = tid & 63, wid = tid >> 6;
  const float* A = var + (size_t)k*D*D;

  for (int idx = tid; idx < TRI; idx += 512) {
    int i = (int)((sqrtf(8.0f*(float)idx + 1.0f) - 1.0f)*0.5f);
    while ((i+1)*(i+2)/2 <= idx) ++i;
    while (i*(i+1)/2 > idx) --i;
    const int p = idx - i*(i+1)/2;
    W[wb(i) + p] = A[i*D + p];
  }
  __syncthreads();

#pragma unroll 1
  for (int jb = 0; jb < 8; ++jb) {
    const int c0 = jb*32, c1 = c0 + 32, m = 256 - c1;

    if (wid == 0 && lane < 32) {
      const int rbase = wb(c0 + lane) + c0;
      float Arow[32];
#pragma unroll
      for (int p = 0; p < 32; ++p) Arow[p] = W[rbase + p];   // p>lane: garbage, never escapes

      float mydinv = 0.0f;
#pragma unroll
      for (int j = 0; j < 32; ++j) {
        const float dj = sqrtf(rdlane(Arow[j], j));
        const float dinv = 1.0f / dj;
        const float c = Arow[j] * dinv;
        Arow[j] = (lane == j) ? dj : c;
        mydinv = (lane == j) ? dinv : mydinv;
#pragma unroll
        for (int p = j + 1; p < 32; ++p) {
          const float cp = rdlane(c, p);
          Arow[p] -= c * cp;
        }
      }

      // G11 = inv(L11), forward substitution fused in place
#pragma unroll
      for (int p = 0; p < 32; ++p) {
        const float lp = (lane > p) ? Arow[p] : 0.0f;
#pragma unroll
        for (int j = 0; j < p; ++j) {
          const float fin = (0.0f - Arow[j]) * mydinv;
          Arow[j] = (lane == p) ? fin : Arow[j];
        }
        Arow[p] = (lane == p) ? mydinv : Arow[p];
#pragma unroll
        for (int j = 0; j < p; ++j) {
          const float gpj = rdlane(Arow[j], p);
          Arow[j] += lp * gpj;
        }
        const float gpp = rdlane(Arow[p], p);
        Arow[p] = (lane > p) ? (lp * gpp) : Arow[p];
      }

#pragma unroll
      for (int j = 0; j < 32; ++j) {
        if (j <= lane) W[rbase + j] = Arow[j];
        Tbuf[lane*36 + j] = (j <= lane) ? Arow[j] : 0.0f;
      }
    }
    __syncthreads();

    // TRSM: 2 threads/row; preload rows (b128), barrier, compute+write
    {
      const int m2 = 2*m;
      const int r = tid >> 1, jh = tid & 1;
      const int rb = wb(c1 + r) + c0;
      float row[32];
      if (tid < m2) {
#pragma unroll
        for (int p4 = 0; p4 < 8; ++p4) {
          const float4 v = *reinterpret_cast<const float4*>(&W[rb + p4*4]);
          row[p4*4+0] = v.x; row[p4*4+1] = v.y; row[p4*4+2] = v.z; row[p4*4+3] = v.w;
        }
      }
      __syncthreads();
      if (tid < m2) {
        const int j0 = jh*16;
#pragma unroll 1
        for (int j = j0; j < j0 + 16; ++j) {
          const float* up = &Tbuf[j*36];
          float s0 = 0.f, s1 = 0.f, s2 = 0.f, s3 = 0.f;
#pragma unroll
          for (int p4 = 0; p4 < 8; ++p4) {
            const float4 u = *reinterpret_cast<const float4*>(&up[p4*4]);
            s0 += row[p4*4+0]*u.x; s1 += row[p4*4+1]*u.y;
            s2 += row[p4*4+2]*u.z; s3 += row[p4*4+3]*u.w;
          }
          W[rb + j] = (s0 + s1) + (s2 + s3);
        }
      }
    }
    __syncthreads();

    // SYRK: trailing triangle -= L21*L21^T, b128 reads along p
    if (m > 0) {
      const int nt = m >> 2, ntri = nt*(nt+1)/2;
      for (int tau = tid; tau < ntri; tau += 512) {
        int ti = (int)((sqrtf(8.0f*(float)tau + 1.0f) - 1.0f)*0.5f);
        while ((ti+1)*(ti+2)/2 <= tau) ++ti;
        while (ti*(ti+1)/2 > tau) --ti;
        const int tl = tau - ti*(ti+1)/2;
        const int i0 = c1 + ti*4, l0 = c1 + tl*4;
        const int ib[4] = {wb(i0)+c0, wb(i0+1)+c0, wb(i0+2)+c0, wb(i0+3)+c0};
        const int lb[4] = {wb(l0)+c0, wb(l0+1)+c0, wb(l0+2)+c0, wb(l0+3)+c0};
        float acc[4][4];
#pragma unroll
        for (int a = 0; a < 4; ++a)
#pragma unroll
          for (int b = 0; b < 4; ++b) acc[a][b] = 0.0f;
#pragma unroll
        for (int p4 = 0; p4 < 8; ++p4) {
          float4 av[4], bv[4];
#pragma unroll
          for (int a = 0; a < 4; ++a) av[a] = *reinterpret_cast<const float4*>(&W[ib[a] + p4*4]);
#pragma unroll
          for (int b = 0; b < 4; ++b) bv[b] = *reinterpret_cast<const float4*>(&W[lb[b] + p4*4]);
#pragma unroll
          for (int a = 0; a < 4; ++a)
#pragma unroll
            for (int b = 0; b < 4; ++b)
              acc[a][b] += av[a].x*bv[b].x + av[a].y*bv[b].y + av[a].z*bv[b].z + av[a].w*bv[b].w;
        }
#pragma unroll
        for (int a = 0; a < 4; ++a)
#pragma unroll
          for (int b = 0; b < 4; ++b) {
            const int rr = i0 + a, cc = l0 + b;
            if (cc <= rr) W[wb(rr) + cc] -= acc[a][b];
          }
      }
    }
    __syncthreads();
  }

  float* Wgk = (float*)(planes + (size_t)k*SLAB_SH);
  for (int idx = tid; idx < WSZ; idx += 512) Wgk[idx] = W[idx];
}

// ---------------------------------------------------------------------------
// K2: column-parallel triangular inversion, 7 blocks/cluster (one J each;
// J=7 has no off-diag work). Each block loads only rows >= 32J, runs the
// in-place column recurrence for J, writes back rows >= 32(J+1) of
// column-block J (disjoint across blocks).  [FROZEN]
// ---------------------------------------------------------------------------
__global__ __launch_bounds__(512, 1) void gmm_inv3(unsigned short* __restrict__ planes)
{
  __shared__ float W[WSZ];
  __shared__ float Tbuf[32*36];

  const int b = blockIdx.x, k = b/7, J = b - 7*(b/7);
  const int tid = threadIdx.x;
  float* Wgk = (float*)(planes + (size_t)k*SLAB_SH);
  const int base = wb(32*J);           // 16B-aligned; rows >= 32J live at [base, WSZ)
  for (int idx = base + tid; idx < WSZ; idx += 512) W[idx] = Wgk[idx];
  __syncthreads();

  const int i0 = tid >> 4;
  const int j0g = (tid & 15) * 2;

#pragma unroll 1
  for (int I = J + 1; I < 8; ++I) {
    float acc0 = 0.f, acc1 = 0.f;
    for (int K = J; K < I; ++K) {
      const int abase = wb(32*I + i0) + 32*K;
      const int brow = 32*K, bcol = 32*J + j0g;
      const bool dK = (K == J);
#pragma unroll
      for (int p4 = 0; p4 < 8; ++p4) {
        const float4 av = *reinterpret_cast<const float4*>(&W[abase + p4*4]);
        const float a4[4] = {av.x, av.y, av.z, av.w};
#pragma unroll
        for (int pp = 0; pp < 4; ++pp) {
          const int p = p4*4 + pp;
          const float2 bv = *reinterpret_cast<const float2*>(&W[wb(brow + p) + bcol]);
          float b0 = bv.x, b1 = bv.y;
          if (dK) { if (j0g > p) b0 = 0.f; if (j0g + 1 > p) b1 = 0.f; }
          acc0 += a4[pp]*b0; acc1 += a4[pp]*b1;
        }
      }
    }
    Tbuf[i0*36 + j0g] = acc0;
    Tbuf[i0*36 + j0g + 1] = acc1;
    __syncthreads();

    float g0 = 0.f, g1 = 0.f;
    const int ubase = wb(32*I + i0) + 32*I;
#pragma unroll
    for (int p4 = 0; p4 < 8; ++p4) {
      const float4 uv = *reinterpret_cast<const float4*>(&W[ubase + p4*4]);
      const float u4[4] = {uv.x, uv.y, uv.z, uv.w};
#pragma unroll
      for (int pp = 0; pp < 4; ++pp) {
        const int p = p4*4 + pp;
        const float u = (p <= i0) ? u4[pp] : 0.f;
        const float2 tv = *reinterpret_cast<const float2*>(&Tbuf[p*36 + j0g]);
        g0 += u*tv.x; g1 += u*tv.y;
      }
    }
    __syncthreads();   // Tbuf reads done before next iter's overwrite
    {
      float2 wv; wv.x = -g0; wv.y = -g1;
      *reinterpret_cast<float2*>(&W[wb(32*I + i0) + 32*J + j0g]) = wv;
    }
    __syncthreads();   // W_IJ visible before next iteration's reads
  }

  // write back this block's G column-block (rows >= 32(J+1), cols [32J,32J+32))
  const int r0 = 32*(J + 1);
  const int nel = (256 - r0) * 32;
  for (int e = tid; e < nel; e += 512) {
    const int r = r0 + (e >> 5), c = 32*J + (e & 31);
    Wgk[wb(r) + c] = W[wb(r) + c];
  }
}

// ---------------------------------------------------------------------------
// K3: pack + t/bias; also zeroes flagcnt (replaces the memset launch —
// pack completes before merge on the serial stream).
// ---------------------------------------------------------------------------
__global__ __launch_bounds__(256, 1) void gmm_pack(
    unsigned short* __restrict__ planes, const float* __restrict__ mu,
    const float* __restrict__ pi, float* __restrict__ tvec,
    float* __restrict__ bias, int* __restrict__ flagcnt)
{
  __shared__ float W[WSZ];
  __shared__ float colbuf[D];
  __shared__ float red[256];
  const int k = blockIdx.x, tid = threadIdx.x;
  if (k == 0 && tid == 0) *flagcnt = 0;
  const float* Wgk = (const float*)(planes + (size_t)k*SLAB_SH);
  for (int idx = tid; idx < WSZ; idx += 256) W[idx] = Wgk[idx];
  colbuf[tid] = mu[k*D + tid];
  __syncthreads();

  {
    const int rb4 = wb(tid);
    float s = 0.0f;
    for (int p = 0; p <= tid; ++p) s += W[rb4 + p]*colbuf[p];
    tvec[k*D + tid] = s;
    red[tid] = s*s;
  }
  __syncthreads();
  for (int st = 128; st > 0; st >>= 1) { if (tid < st) red[tid] += red[tid+st]; __syncthreads(); }
  const float t2 = red[0];
  __syncthreads();
  red[tid] = logf(W[wb(tid) + tid]);
  __syncthreads();
  for (int st = 128; st > 0; st >>= 1) { if (tid < st) red[tid] += red[tid+st]; __syncthreads(); }
  if (tid == 0) bias[k] = logf(pi[k]) + red[0] - 0.5f*t2;
  __syncthreads();

  unsigned short* slab = planes + (size_t)k*SLAB_SH;
  for (int e = tid; e < SH_PER_CL; e += 256) {
    const int f = e >> 9, wrd = e & 511, l = wrd >> 3, j = wrd & 7;
    const int I = (f>=1)+(f>=2)+(f>=4)+(f>=6)+(f>=9)+(f>=12)+(f>=16)+(f>=20)
                +(f>=25)+(f>=30)+(f>=36)+(f>=42)+(f>=49)+(f>=56)+(f>=64);
    const int kc = f - frag_off(I);
    const int li = l & 15, hh = l >> 4;
    const int p = kc*32 + hh*8 + j, i2 = I*16 + li;
    const float g = (p <= i2) ? W[wb(i2) + p] : 0.0f;   // Gt[p][i] = G[i][p]
    const unsigned short hb = f2bf(g); const float hf = bf2f(hb);
    const float r1 = g - hf;
    const unsigned short lb = f2bf(r1); const float lf = bf2f(lb);
    const unsigned short rb = f2bf(r1 - lf);
    slab[e] = hb;
    slab[SH_PER_CL + e] = lb;
    slab[2*SH_PER_CL + e] = rb;
  }
}

// ---------------------------------------------------------------------------
// K4: MFMA scoring, split-2, LDS-staged B (h+l planes, 147 KB), XCD-local
// block mapping.  [FROZEN]
// ---------------------------------------------------------------------------
__global__ __launch_bounds__(512, 1) void gmm_score_mfma(
    const float* __restrict__ x, const unsigned short* __restrict__ planes,
    const float* __restrict__ tvec, const float* __restrict__ bias,
    float* __restrict__ partq)
{
  __shared__ uint4 shb[9216];   // 147456 B: plane-h + plane-l
  const int tid = threadIdx.x, lane = tid & 63, w = tid >> 6;
  const int li = lane & 15, h = lane >> 4;
  const int kq = blockIdx.x & 7, ntile = blockIdx.x >> 3;   // XCD-local octants
  const int n0 = ntile*256 + w*32;

  short8 ah[2][8], al[2][8];
#pragma unroll
  for (int s = 0; s < 2; ++s) {
    const float* xr = x + (size_t)(n0 + s*16 + li)*D;
#pragma unroll
    for (int kc = 0; kc < 8; ++kc) {
      const float4 v0 = *reinterpret_cast<const float4*>(xr + kc*32 + h*8);
      const float4 v1 = *reinterpret_cast<const float4*>(xr + kc*32 + h*8 + 4);
      const float xv[8] = {v0.x, v0.y, v0.z, v0.w, v1.x, v1.y, v1.z, v1.w};
#pragma unroll
      for (int j = 0; j < 8; ++j) {
        const unsigned short hb = f2bf(xv[j]);
        ah[s][kc][j] = (short)hb;
        al[s][kc][j] = (short)f2bf(xv[j] - bf2f(hb));
      }
    }
  }

  float best0[4], sec0[4], best1[4], sec1[4];
  int bk0[4], bk1[4];
#pragma unroll
  for (int j = 0; j < 4; ++j) {
    best0[j] = -3.0e38f; sec0[j] = -3.0e38f; bk0[j] = 0;
    best1[j] = -3.0e38f; sec1[j] = -3.0e38f; bk1[j] = 0;
  }

  const unsigned short* shs = reinterpret_cast<const unsigned short*>(shb);

#pragma unroll 1
  for (int kk = 0; kk < 8; ++kk) {
    const int k = kq*8 + kk;
    __syncthreads();   // previous compute done before restage
    {
      const uint4* g4 = reinterpret_cast<const uint4*>(planes + (size_t)k*SLAB_SH);
#pragma unroll
      for (int it = 0; it < 18; ++it)
        shb[it*512 + tid] = g4[it*512 + tid];
    }
    __syncthreads();

    const float* tk = tvec + k*D;
    float p0[4] = {0.f,0.f,0.f,0.f}, p1[4] = {0.f,0.f,0.f,0.f};
#pragma unroll
    for (int I = 0; I < 16; ++I) {
      const int fb = frag_off(I);
      const int kcnt = (I + 2) >> 1;
      f32x4 a0A = {0.f,0.f,0.f,0.f}, a0B = {0.f,0.f,0.f,0.f}, a0C = {0.f,0.f,0.f,0.f};
      f32x4 a1A = {0.f,0.f,0.f,0.f}, a1B = {0.f,0.f,0.f,0.f}, a1C = {0.f,0.f,0.f,0.f};
#pragma unroll
      for (int kc = 0; kc < kcnt; ++kc) {
        const int fo = (fb + kc)*512 + lane*8;
        const short8 bh = *reinterpret_cast<const short8*>(shs + fo);
        const short8 bl = *reinterpret_cast<const short8*>(shs + 36864 + fo);
        a0A = __builtin_amdgcn_mfma_f32_16x16x32_bf16(ah[0][kc], bh, a0A, 0, 0, 0);
        a1A = __builtin_amdgcn_mfma_f32_16x16x32_bf16(ah[1][kc], bh, a1A, 0, 0, 0);
        a0B = __builtin_amdgcn_mfma_f32_16x16x32_bf16(al[0][kc], bh, a0B, 0, 0, 0);
        a1B = __builtin_amdgcn_mfma_f32_16x16x32_bf16(al[1][kc], bh, a1B, 0, 0, 0);
        a0C = __builtin_amdgcn_mfma_f32_16x16x32_bf16(ah[0][kc], bl, a0C, 0, 0, 0);
        a1C = __builtin_amdgcn_mfma_f32_16x16x32_bf16(ah[1][kc], bl, a1C, 0, 0, 0);
      }
      const float t = tk[I*16 + li];
#pragma unroll
      for (int j = 0; j < 4; ++j) {
        float y = a0A[j] + (a0B[j] + a0C[j]); p0[j] += y*(t - 0.5f*y);
        y = a1A[j] + (a1B[j] + a1C[j]);       p1[j] += y*(t - 0.5f*y);
      }
    }
#pragma unroll
    for (int mloc = 1; mloc < 16; mloc <<= 1) {
#pragma unroll
      for (int j = 0; j < 4; ++j) {
        p0[j] += __shfl_xor(p0[j], mloc, 64);
        p1[j] += __shfl_xor(p1[j], mloc, 64);
      }
    }
    const float bs = bias[k];
#pragma unroll
    for (int j = 0; j < 4; ++j) {
      const float s0v = bs + p0[j];
      if (s0v > best0[j]) { sec0[j] = best0[j]; best0[j] = s0v; bk0[j] = k; }
      else if (s0v > sec0[j]) sec0[j] = s0v;
      const float s1v = bs + p1[j];
      if (s1v > best1[j]) { sec1[j] = best1[j]; best1[j] = s1v; bk1[j] = k; }
      else if (s1v > sec1[j]) sec1[j] = s1v;
    }
  }

  if (li == 0) {
#pragma unroll
    for (int j = 0; j < 4; ++j) {
      const size_t r0 = ((size_t)kq*NPTS + n0 + h*4 + j)*3;
      partq[r0] = best0[j]; partq[r0+1] = __int_as_float(bk0[j]); partq[r0+2] = sec0[j];
      const size_t r1 = ((size_t)kq*NPTS + n0 + 16 + h*4 + j)*3;
      partq[r1] = best1[j]; partq[r1+1] = __int_as_float(bk1[j]); partq[r1+2] = sec1[j];
    }
  }
}

// ---------------------------------------------------------------------------
// K5: merge 8 octants; flag small-margin points.  [FROZEN]
// ---------------------------------------------------------------------------
__global__ __launch_bounds__(256) void gmm_merge(
    const float* __restrict__ partq, int* __restrict__ out,
    int* __restrict__ flaglist, int* __restrict__ flagcnt)
{
  const int n = blockIdx.x*256 + threadIdx.x;
  float b = -3.0e38f, s2 = -3.0e38f; int bk = 0;
#pragma unroll
  for (int q = 0; q < 8; ++q) {
    const size_t o = ((size_t)q*NPTS + n)*3;
    const float bq = partq[o];
    const int kq_ = __float_as_int(partq[o+1]);
    const float sq = partq[o+2];
    if (bq > b) { s2 = fmaxf(b, sq); b = bq; bk = kq_; }
    else        { s2 = fmaxf(s2, bq); }
  }
  out[n] = bk;
  if (b - s2 < 0.25f) {
    const int idx = atomicAdd(flagcnt, 1);
    flaglist[idx] = n;
  }
}

// ---------------------------------------------------------------------------
// K6: exact re-score, split-3, cluster-per-block, non-spilling. Writes
// escore transposed: escore[slot][k] (contiguous per slot for emerge).
// ---------------------------------------------------------------------------
__global__ __launch_bounds__(256, 1) void gmm_escore(
    const float* __restrict__ x, const unsigned short* __restrict__ planes,
    const float* __restrict__ tvec, const float* __restrict__ bias,
    const int* __restrict__ flaglist, const int* __restrict__ flagcnt,
    float* __restrict__ escore)
{
  const int bid = blockIdx.x;
  const int k = bid & 63, gs = bid >> 6;
  const int tid = threadIdx.x, lane = tid & 63, w = tid >> 6;
  const int li = lane & 15, h = lane >> 4;
  const int cnt = *flagcnt;
  if (cnt == 0) return;

  const unsigned short* bhB = planes + (size_t)k*SLAB_SH;
  const unsigned short* blB = bhB + SH_PER_CL;
  const unsigned short* brB = bhB + 2*SH_PER_CL;
  const float* tk = tvec + k*D;
  const float bs = bias[k];

#pragma unroll 1
  for (int g = gs*4 + w; g*16 < cnt; g += 12) {
    const int slot = g*16 + li;
    const int row = (slot < cnt) ? flaglist[slot] : 0;

    short8 ah[8], al[8], ar[8];
    const float* xr = x + (size_t)row*D;
#pragma unroll
    for (int kc = 0; kc < 8; ++kc) {
      const float4 v0 = *reinterpret_cast<const float4*>(xr + kc*32 + h*8);
      const float4 v1 = *reinterpret_cast<const float4*>(xr + kc*32 + h*8 + 4);
      const float xv[8] = {v0.x, v0.y, v0.z, v0.w, v1.x, v1.y, v1.z, v1.w};
#pragma unroll
      for (int j = 0; j < 8; ++j) {
        const unsigned short hb = f2bf(xv[j]); const float hf = bf2f(hb);
        const float r1 = xv[j] - hf;
        const unsigned short lb = f2bf(r1); const float lf = bf2f(lb);
        ah[kc][j] = (short)hb; al[kc][j] = (short)lb; ar[kc][j] = (short)f2bf(r1 - lf);
      }
    }

    float p[4] = {0.f,0.f,0.f,0.f};
#pragma unroll 1
    for (int I = 0; I < 16; ++I) {
      const int fb = frag_off(I);
      const int kcnt = (I + 2) >> 1;
      f32x4 accA = {0.f,0.f,0.f,0.f}, accB = {0.f,0.f,0.f,0.f};
#pragma unroll
      for (int kc = 0; kc < 8; ++kc) {
        if (kc < kcnt) {   // wave-uniform: s_cbranch skip, no divergence
          const int fo = (fb + kc)*512 + lane*8;
          const short8 bh = *reinterpret_cast<const short8*>(bhB + fo);
          const short8 bl = *reinterpret_cast<const short8*>(blB + fo);
          const short8 br = *reinterpret_cast<const short8*>(brB + fo);
          accA = __builtin_amdgcn_mfma_f32_16x16x32_bf16(ah[kc], bh, accA, 0, 0, 0);
          accB = __builtin_amdgcn_mfma_f32_16x16x32_bf16(al[kc], bh, accB, 0, 0, 0);
          accB = __builtin_amdgcn_mfma_f32_16x16x32_bf16(ar[kc], bh, accB, 0, 0, 0);
          accB = __builtin_amdgcn_mfma_f32_16x16x32_bf16(ah[kc], bl, accB, 0, 0, 0);
          accB = __builtin_amdgcn_mfma_f32_16x16x32_bf16(al[kc], bl, accB, 0, 0, 0);
          accB = __builtin_amdgcn_mfma_f32_16x16x32_bf16(ah[kc], br, accB, 0, 0, 0);
        }
      }
      const float t = tk[I*16 + li];
#pragma unroll
      for (int j = 0; j < 4; ++j) {
        const float y = accA[j] + accB[j];
        p[j] += y*(t - 0.5f*y);
      }
    }
#pragma unroll
    for (int mloc = 1; mloc < 16; mloc <<= 1) {
#pragma unroll
      for (int j = 0; j < 4; ++j) p[j] += __shfl_xor(p[j], mloc, 64);
    }
    if (li == 0) {
#pragma unroll
      for (int j = 0; j < 4; ++j) {
        const int slot2 = g*16 + h*4 + j;
        if (slot2 < cnt) escore[(size_t)slot2*KC + k] = bs + p[j];
      }
    }
  }
}

// ---------------------------------------------------------------------------
// K7: exact merge — contiguous 64-way argmax per flagged slot (ascending k,
// strict > => first-occurrence semantics).
// ---------------------------------------------------------------------------
__global__ __launch_bounds__(256) void gmm_emerge(
    const float* __restrict__ escore, const int* __restrict__ flaglist,
    const int* __restrict__ flagcnt, int* __restrict__ out)
{
  const int cnt = *flagcnt;
  const int s = blockIdx.x*256 + threadIdx.x;
  if (s >= cnt) return;
  const float* es = escore + (size_t)s*KC;
  float b = es[0]; int bk = 0;
#pragma unroll 1
  for (int k = 1; k < KC; ++k) {
    const float v = es[k];
    if (v > b) { b = v; bk = k; }
  }
  out[flaglist[s]] = bk;
}

extern "C" void kernel_launch(void* const* d_in, const int* in_sizes, int n_in,
                              void* d_out, int out_size, void* d_ws, size_t ws_size,
                              hipStream_t stream)
{
  const float* x   = (const float*)d_in[0];   // (8192, 256)
  const float* mu  = (const float*)d_in[1];   // (64, 256)
  const float* var = (const float*)d_in[2];   // (64, 256, 256)
  const float* pi  = (const float*)d_in[3];   // (64,)

  char* ws = (char*)d_ws;
  unsigned short* planes = (unsigned short*)ws;                      // 64 cluster slabs, 14.16 MB
  float* tvec = (float*)(ws + KC*SLAB_SH*sizeof(unsigned short));    // 64 KB
  float* bias = tvec + KC*D;                                         // 64 floats (pad to 256)
  int* flaglist = (int*)(bias + 256);                                // 8192 ints
  int* flagcnt = flaglist + NPTS;                                    // 1 int (pad 64)
  float* partq = (float*)(flagcnt + 64);                             // 8*8192*3 floats
  float* escore = partq;                                             // aliases partq (dead after merge); NPTS*KC floats
  int* out = (int*)d_out;

  gmm_chol<<<KC, 512, 0, stream>>>(var, planes);
  gmm_inv3<<<7*KC, 512, 0, stream>>>(planes);
  gmm_pack<<<KC, 256, 0, stream>>>(planes, mu, pi, tvec, bias, flagcnt);
  gmm_score_mfma<<<256, 512, 0, stream>>>(x, planes, tvec, bias, partq);
  gmm_merge<<<NPTS/256, 256, 0, stream>>>(partq, out, flaglist, flagcnt);
  gmm_escore<<<3*KC, 256, 0, stream>>>(x, planes, tvec, bias, flaglist, flagcnt, escore);
  gmm_emerge<<<NPTS/256, 256, 0, stream>>>(escore, flaglist, flagcnt, out);
}